// Round 6
// baseline (1320.822 us; speedup 1.0000x reference)
//
#include <hip/hip_runtime.h>
#include <math.h>

#define TT 2048
#define UU 64
#define BB 256
#define NW 9             // 8 producer waves (4 gates x 2 k-halves) + 1 consumer
#define NTHR (NW * 64)

// Fast activations on v_exp_f32 / v_rcp_f32 (validated absmax 9.5e-7, thr 3.45e-6).
__device__ __forceinline__ float frcp(float x) { return __builtin_amdgcn_rcpf(x); }
__device__ __forceinline__ float fsigmoid(float x) { return frcp(1.0f + __expf(-x)); }
__device__ __forceinline__ float ftanh(float x) { return 1.0f - 2.0f * frcp(1.0f + __expf(2.0f * x)); }

// One block per batch (256 blocks = 1/CU), 576 threads = 9 waves.
// Rounds 3/4/5 showed the allocator refuses to hold 64 weight floats/lane
// (VGPR_Count 64/164/40 -> spill -> 64 KB/step scratch re-reads ~= the whole
// 1480 cyc/step). Fix: halve per-lane weights. Producer wave w=(g,q):
// lane u owns column c=g*64+u over k in [32q,32q+32) -> 32 weights in 8 named
// float4s (~55 VGPRs total, inside the allocator's comfort zone).
// Per step (ONE barrier): 32 readlane+FMA partial matvec (h register-resident,
// no LDS h), write zp[p][2c+q]; barrier; read 4 float2 partial pairs, sum
// halves, redundantly update unit um=32q+(u&31) in-registers for next step's
// readlanes. zp double-buffered => race-free with one barrier.
// Consumer wave: round-5's lagged layer-1 (butterfly h.W1, (c1,h1) update,
// banked coalesced stores). All waves execute identical barrier counts.
__global__ __launch_bounds__(NTHR, 1) __attribute__((amdgpu_waves_per_eu(1)))
void lstm_ts_kernel(
    const float* __restrict__ x, const float* __restrict__ W0,
    const float* __restrict__ b0, const float* __restrict__ W1,
    const float* __restrict__ b1, const float* __restrict__ Wd,
    const float* __restrict__ bd, float* __restrict__ out)
{
    __shared__ float xbuf[TT];
    __shared__ __align__(8) float zp[2][512];   // [buf][c*2+q] gate partials
    __shared__ float ring[2][UU];
    __shared__ float red[NW];

    const int tid = threadIdx.x;
    const int wid = tid >> 6;
    const int u = tid & 63;
    const int b = blockIdx.x;
    const float* xrow = x + b * TT;
    float* outrow = out + b * TT;

    // ---- prologue: stage x, sum of squares over T ----
    float ss = 0.f;
    for (int i = tid; i < TT; i += NTHR) {
        float v = xrow[i];
        xbuf[i] = v;
        ss += v * v;
    }
    #pragma unroll
    for (int m = 1; m < 64; m <<= 1) ss += __shfl_xor(ss, m, 64);
    if (u == 0) red[wid] = ss;
    __syncthreads();  // B_pro

    if (wid < 8) {
        // ================= PRODUCER (g = gate, q = k-half) =================
        const int g = wid >> 1;
        const int q = wid & 1;
        const int c = g * 64 + u;          // owned output column
        const int um = q * 32 + (u & 31);  // unit updated redundantly

        float sq = 0.f;
        #pragma unroll
        for (int i = 0; i < NW; ++i) sq += red[i];
        const float scale = 1.0f / sqrtf(fmaxf(sq, 1e-12f));  // precise, once

        // 8 named float4 = 32 weight VGPRs: rows (1 + 32q + j), column c
        #define DECLW(i) float4 Wf##i; \
            Wf##i.x = W0[(1 + 32*q + 4*i + 0) * 256 + c]; \
            Wf##i.y = W0[(1 + 32*q + 4*i + 1) * 256 + c]; \
            Wf##i.z = W0[(1 + 32*q + 4*i + 2) * 256 + c]; \
            Wf##i.w = W0[(1 + 32*q + 4*i + 3) * 256 + c];
        DECLW(0) DECLW(1) DECLW(2) DECLW(3)
        DECLW(4) DECLW(5) DECLW(6) DECLW(7)
        #undef DECLW

        // x-weight and bias folded into the q==0 partial only
        const float wxs = (q == 0) ? W0[c] * scale : 0.f;
        const float bcv = (q == 0) ? b0[c] : 0.f;

        float c0 = 0.f, h = 0.f;

        for (int t = 0; t < TT; ++t) {
            const int p = t & 1;
            const int hi = __float_as_int(h);

            // ---- partial matvec over this wave's 32 k's (h in registers) ----
            float a0 = 0.f, a1 = 0.f, a2 = 0.f, a3 = 0.f;
            #define MAC4(i) \
                a0 = fmaf(__int_as_float(__builtin_amdgcn_readlane(hi, 4*i+0)), Wf##i.x, a0); \
                a1 = fmaf(__int_as_float(__builtin_amdgcn_readlane(hi, 4*i+1)), Wf##i.y, a1); \
                a2 = fmaf(__int_as_float(__builtin_amdgcn_readlane(hi, 4*i+2)), Wf##i.z, a2); \
                a3 = fmaf(__int_as_float(__builtin_amdgcn_readlane(hi, 4*i+3)), Wf##i.w, a3);
            MAC4(0) MAC4(1) MAC4(2) MAC4(3)
            MAC4(4) MAC4(5) MAC4(6) MAC4(7)
            #undef MAC4

            zp[p][2 * c + q] = ((a0 + a1) + (a2 + a3)) + fmaf(xbuf[t], wxs, bcv);
            __syncthreads();  // B(t)

            // ---- redundant unit update: read 4 partial pairs, sum halves ----
            const float2* zp2 = reinterpret_cast<const float2*>(zp[p]);
            const float2 vi = zp2[um];
            const float2 vj = zp2[64 + um];
            const float2 vf = zp2[128 + um];
            const float2 vo = zp2[192 + um];
            const float zi = vi.x + vi.y;
            const float zj = vj.x + vj.y;
            const float zf = vf.x + vf.y;
            const float zo = vo.x + vo.y;
            c0 = fsigmoid(zf + 1.0f) * c0 + fsigmoid(zi) * ftanh(zj);
            h = fsigmoid(zo) * ftanh(c0);
            if (g == 0 && u < 32) ring[p][um] = h;  // publish h(t) for consumer
        }
        __syncthreads();  // B_epi
    } else {
        // ================= CONSUMER: layer 1 + dense + store =================
        const float w1v0 = W1[u * 4 + 0], w1v1 = W1[u * 4 + 1];
        const float w1v2 = W1[u * 4 + 2], w1v3 = W1[u * 4 + 3];
        const float w1h0 = W1[256], w1h1 = W1[257], w1h2 = W1[258], w1h3 = W1[259];
        const float b10 = b1[0], b11 = b1[1], b12 = b1[2], b13 = b1[3];
        const float wd = Wd[0], bdv = bd[0];

        float c1 = 0.f, h1 = 0.f, oval = 0.f;

        #define L1STEP(s) { \
            const float hu = ring[(s) & 1][u]; \
            float p0 = hu * w1v0, p1 = hu * w1v1, p2 = hu * w1v2, p3 = hu * w1v3; \
            _Pragma("unroll") \
            for (int m = 1; m < 64; m <<= 1) { \
                p0 += __shfl_xor(p0, m, 64); \
                p1 += __shfl_xor(p1, m, 64); \
                p2 += __shfl_xor(p2, m, 64); \
                p3 += __shfl_xor(p3, m, 64); \
            } \
            const float z1i = p0 + fmaf(h1, w1h0, b10); \
            const float z1j = p1 + fmaf(h1, w1h1, b11); \
            const float z1f = p2 + fmaf(h1, w1h2, b12); \
            const float z1o = p3 + fmaf(h1, w1h3, b13); \
            c1 = fsigmoid(z1f + 1.0f) * c1 + fsigmoid(z1i) * ftanh(z1j); \
            h1 = fsigmoid(z1o) * ftanh(c1); \
            const float ov = fmaf(h1, wd, bdv); \
            if (((s) & 63) == u) oval = ov; \
            if (((s) & 63) == 63) outrow[((s) & ~63) + u] = oval; \
        }

        for (int t = 0; t < TT; ++t) {
            __syncthreads();  // B(t)
            if (t > 0) L1STEP(t - 1)   // ring[(t-1)&1] written before B(t)
        }
        __syncthreads();  // B_epi — makes ring[(TT-1)&1] visible
        L1STEP(TT - 1)
        #undef L1STEP
    }
}

extern "C" void kernel_launch(void* const* d_in, const int* in_sizes, int n_in,
                              void* d_out, int out_size, void* d_ws, size_t ws_size,
                              hipStream_t stream) {
    const float* x  = (const float*)d_in[0];
    const float* W0 = (const float*)d_in[1];
    const float* b0 = (const float*)d_in[2];
    const float* W1 = (const float*)d_in[3];
    const float* b1 = (const float*)d_in[4];
    const float* Wd = (const float*)d_in[5];
    const float* bd = (const float*)d_in[6];
    float* out = (float*)d_out;
    lstm_ts_kernel<<<BB, NTHR, 0, stream>>>(x, W0, b0, W1, b1, Wd, bd, out);
}

// Round 7
// 1280.739 us; speedup vs baseline: 1.0313x; 1.0313x over previous
//
#include <hip/hip_runtime.h>
#include <math.h>

#define TT 2048
#define UU 64
#define BB 256
#define NW 9             // 8 producer waves (4 gates x 2 k-halves) + 1 consumer
#define NTHR (NW * 64)

// Fast activations on v_exp_f32 / v_rcp_f32 (validated absmax 9.5e-7, thr 3.45e-6).
__device__ __forceinline__ float frcp(float x) { return __builtin_amdgcn_rcpf(x); }
__device__ __forceinline__ float fsigmoid(float x) { return frcp(1.0f + __expf(-x)); }
__device__ __forceinline__ float ftanh(float x) { return 1.0f - 2.0f * frcp(1.0f + __expf(2.0f * x)); }

// R5/R6 post-mortem: allocator caps arch-VGPRs at ~36-64 for multi-wave blocks
// and spills ALL weight state -> 64 KB/CU/step of L2 re-reads ~= the whole
// 1500 cyc/step (identical in R5 and R6 despite different splits). Fix: stash
// the 32 per-lane weights in AGPRs (file is idle — no MFMA here) via explicit
// v_accvgpr_write/read inline asm. Volatile reads can't be hoisted (would
// recreate VGPR pressure) or remat'd from memory. VGPR working set ~25 fits
// any budget -> nothing left to spill.
// Structure otherwise = R6: 8 producer waves (g=gate, q=k-half), lane u owns
// column c=g*64+u over k in [32q,32q+32); ONE barrier/step; redundant unit
// update keeps h register-resident for readlane broadcast; consumer wave runs
// lagged layer-1 + dense + coalesced stores. zp partials now in two b32
// arrays (zpa/zpb): reads are 2-way-broadcast conflict-free (R6 had 8.4M
// bank-conflict cycles from the strided float2 layout).
__global__ __launch_bounds__(NTHR, 1) __attribute__((amdgpu_waves_per_eu(2, 2)))
void lstm_ts_kernel(
    const float* __restrict__ x, const float* __restrict__ W0,
    const float* __restrict__ b0, const float* __restrict__ W1,
    const float* __restrict__ b1, const float* __restrict__ Wd,
    const float* __restrict__ bd, float* __restrict__ out)
{
    __shared__ float xbuf[TT];
    __shared__ float zpa[2][256];   // q=0 gate partials, [buf][c]
    __shared__ float zpb[2][256];   // q=1 gate partials, [buf][c]
    __shared__ float ring[2][UU];
    __shared__ float red[NW];

    const int tid = threadIdx.x;
    const int wid = tid >> 6;
    const int u = tid & 63;
    const int b = blockIdx.x;
    const float* xrow = x + b * TT;
    float* outrow = out + b * TT;

    // ---- prologue: stage x, sum of squares over T ----
    float ss = 0.f;
    for (int i = tid; i < TT; i += NTHR) {
        float v = xrow[i];
        xbuf[i] = v;
        ss += v * v;
    }
    #pragma unroll
    for (int m = 1; m < 64; m <<= 1) ss += __shfl_xor(ss, m, 64);
    if (u == 0) red[wid] = ss;
    __syncthreads();  // B_pro

    if (wid < 8) {
        // ================= PRODUCER (g = gate, q = k-half) =================
        const int g = wid >> 1;
        const int q = wid & 1;
        const int c = g * 64 + u;          // owned output column
        const int um = q * 32 + (u & 31);  // unit updated redundantly

        float sq = 0.f;
        #pragma unroll
        for (int i = 0; i < NW; ++i) sq += red[i];
        const float scale = 1.0f / sqrtf(fmaxf(sq, 1e-12f));  // precise, once

        // ---- 32 weights -> AGPR stash (idle file; allocator can't touch) ----
        #define DECLS(k) float agw##k; { \
            const float tmp_ = W0[(1 + 32 * q + (k)) * 256 + c]; \
            asm volatile("v_accvgpr_write_b32 %0, %1" : "=a"(agw##k) : "v"(tmp_)); }
        DECLS(0)  DECLS(1)  DECLS(2)  DECLS(3)  DECLS(4)  DECLS(5)  DECLS(6)  DECLS(7)
        DECLS(8)  DECLS(9)  DECLS(10) DECLS(11) DECLS(12) DECLS(13) DECLS(14) DECLS(15)
        DECLS(16) DECLS(17) DECLS(18) DECLS(19) DECLS(20) DECLS(21) DECLS(22) DECLS(23)
        DECLS(24) DECLS(25) DECLS(26) DECLS(27) DECLS(28) DECLS(29) DECLS(30) DECLS(31)
        #undef DECLS

        // x-weight and bias folded into the q==0 partial only
        const float wxs = (q == 0) ? W0[c] * scale : 0.f;
        const float bcv = (q == 0) ? b0[c] : 0.f;

        float c0 = 0.f, h = 0.f;

        for (int t = 0; t < TT; ++t) {
            const int p = t & 1;
            const int hi = __float_as_int(h);

            // ---- partial matvec over this wave's 32 k's ----
            // h[32q+k] lives in lane k of THIS wave (redundant update below).
            float a0 = 0.f, a1 = 0.f, a2 = 0.f, a3 = 0.f;
            #define MACK(k, ch) { float wv_; \
                asm volatile("v_accvgpr_read_b32 %0, %1" : "=v"(wv_) : "a"(agw##k)); \
                ch = fmaf(__int_as_float(__builtin_amdgcn_readlane(hi, k)), wv_, ch); }
            MACK(0,  a0) MACK(1,  a1) MACK(2,  a2) MACK(3,  a3)
            MACK(4,  a0) MACK(5,  a1) MACK(6,  a2) MACK(7,  a3)
            MACK(8,  a0) MACK(9,  a1) MACK(10, a2) MACK(11, a3)
            MACK(12, a0) MACK(13, a1) MACK(14, a2) MACK(15, a3)
            MACK(16, a0) MACK(17, a1) MACK(18, a2) MACK(19, a3)
            MACK(20, a0) MACK(21, a1) MACK(22, a2) MACK(23, a3)
            MACK(24, a0) MACK(25, a1) MACK(26, a2) MACK(27, a3)
            MACK(28, a0) MACK(29, a1) MACK(30, a2) MACK(31, a3)
            #undef MACK

            const float z = ((a0 + a1) + (a2 + a3)) + fmaf(xbuf[t], wxs, bcv);
            (q ? zpb[p] : zpa[p])[c] = z;
            __syncthreads();  // B(t)

            // ---- redundant unit update: 8 broadcast b32 reads, sum halves ----
            const float zi = zpa[p][um]       + zpb[p][um];
            const float zj = zpa[p][64 + um]  + zpb[p][64 + um];
            const float zf = zpa[p][128 + um] + zpb[p][128 + um];
            const float zo = zpa[p][192 + um] + zpb[p][192 + um];
            c0 = fsigmoid(zf + 1.0f) * c0 + fsigmoid(zi) * ftanh(zj);
            h = fsigmoid(zo) * ftanh(c0);
            if (g == 0 && u < 32) ring[p][um] = h;  // publish h(t) for consumer
        }
        __syncthreads();  // B_epi
    } else {
        // ================= CONSUMER: layer 1 + dense + store =================
        const float w1v0 = W1[u * 4 + 0], w1v1 = W1[u * 4 + 1];
        const float w1v2 = W1[u * 4 + 2], w1v3 = W1[u * 4 + 3];
        const float w1h0 = W1[256], w1h1 = W1[257], w1h2 = W1[258], w1h3 = W1[259];
        const float b10 = b1[0], b11 = b1[1], b12 = b1[2], b13 = b1[3];
        const float wd = Wd[0], bdv = bd[0];

        float c1 = 0.f, h1 = 0.f, oval = 0.f;

        #define L1STEP(s) { \
            const float hu = ring[(s) & 1][u]; \
            float p0 = hu * w1v0, p1 = hu * w1v1, p2 = hu * w1v2, p3 = hu * w1v3; \
            _Pragma("unroll") \
            for (int m = 1; m < 64; m <<= 1) { \
                p0 += __shfl_xor(p0, m, 64); \
                p1 += __shfl_xor(p1, m, 64); \
                p2 += __shfl_xor(p2, m, 64); \
                p3 += __shfl_xor(p3, m, 64); \
            } \
            const float z1i = p0 + fmaf(h1, w1h0, b10); \
            const float z1j = p1 + fmaf(h1, w1h1, b11); \
            const float z1f = p2 + fmaf(h1, w1h2, b12); \
            const float z1o = p3 + fmaf(h1, w1h3, b13); \
            c1 = fsigmoid(z1f + 1.0f) * c1 + fsigmoid(z1i) * ftanh(z1j); \
            h1 = fsigmoid(z1o) * ftanh(c1); \
            const float ov = fmaf(h1, wd, bdv); \
            if (((s) & 63) == u) oval = ov; \
            if (((s) & 63) == 63) outrow[((s) & ~63) + u] = oval; \
        }

        for (int t = 0; t < TT; ++t) {
            __syncthreads();  // B(t)
            if (t > 0) L1STEP(t - 1)   // ring[(t-1)&1] written before B(t)
        }
        __syncthreads();  // B_epi — makes ring[(TT-1)&1] visible
        L1STEP(TT - 1)
        #undef L1STEP
    }
}

extern "C" void kernel_launch(void* const* d_in, const int* in_sizes, int n_in,
                              void* d_out, int out_size, void* d_ws, size_t ws_size,
                              hipStream_t stream) {
    const float* x  = (const float*)d_in[0];
    const float* W0 = (const float*)d_in[1];
    const float* b0 = (const float*)d_in[2];
    const float* W1 = (const float*)d_in[3];
    const float* b1 = (const float*)d_in[4];
    const float* Wd = (const float*)d_in[5];
    const float* bd = (const float*)d_in[6];
    float* out = (float*)d_out;
    lstm_ts_kernel<<<BB, NTHR, 0, stream>>>(x, W0, b0, W1, b1, Wd, bd, out);
}